// Round 20
// baseline (791.464 us; speedup 1.0000x reference)
//
#include <hip/hip_runtime.h>
#include <math.h>

// B=32, R=16384, C=16, IC=16, OC=16, 3 routing iterations.
// x: (B,C,IC) fp32; W: (R,C,OC,IC) fp32 (256 MB); out: (B,C,OC) fp32.
//
// R20: occupancy experiment. All R10-R18 variants ran 16 waves/CU (1024
// blocks x 8 waves, 2 blocks/CU) and all pinned at ~1.7 TB/s effective route
// throughput regardless of structure (registers/pages/request-shape/VALU/
// MLP all falsified). Untested variable: WAVE CONCURRENCY. This round:
// routes = 256-thr blocks (4 waves), grid (16,128) -> 2048 blocks, 8/CU
// co-resident = 32 waves/CU (100%). Register diet for the 64-VGPR cap that
// launch_bounds(256,8) pins (R4-R8 allocator law): f[4] prefetch (R17-proven
// adequate), live ~56. Epilogue tree 4-wave (8.7 KB LDS -> 8 blocks/CU ok).
// Carried: W16 fragment repack + split conv (R18; R19's fused convsum was
// VALU-bound, reverted), single-term fp16 MFMA (absmax 3.9e-3 vs 1.5e-2),
// no cooperative launch (R12), no fusion barriers (R16).
// Accounting: total = ~160us workspace-poison fill (1 GB, unavoidable) +
// conv ~60 + 3 routes + smalls.

typedef _Float16 half8_t __attribute__((ext_vector_type(8)));
typedef float f32x16_t __attribute__((ext_vector_type(16)));

// ---------------------------------------------------------------------------
// k_conv: W fp32 -> W16 fp16 fragment layout (R17/R18-proven).
// One thread = 8 elements (32 B dense read, 16 B write).
// W16 layout (halves): ((c*8192 + (r>>1))*64 + ((r&1)*16 + o + 32*kh))*8,
// element j = W[r][c][o][8kh+j] -- the mfma_32x32x16 A-fragment.
// ---------------------------------------------------------------------------
__global__ __launch_bounds__(256) void k_conv(const float4* __restrict__ W4,
                                              _Float16* __restrict__ W16) {
    int t = blockIdx.x * 256 + threadIdx.x;        // [0, 8388608)
    int kh = t & 1, o = (t >> 1) & 15, c = (t >> 5) & 15, r = t >> 9;
    float4 a = W4[(size_t)t * 2], b = W4[(size_t)t * 2 + 1];
    half8_t h;
    h[0] = (_Float16)a.x; h[1] = (_Float16)a.y; h[2] = (_Float16)a.z; h[3] = (_Float16)a.w;
    h[4] = (_Float16)b.x; h[5] = (_Float16)b.y; h[6] = (_Float16)b.z; h[7] = (_Float16)b.w;
    size_t dst = ((size_t)(c * 8192 + (r >> 1)) * 64
                  + ((r & 1) * 16 + o + 32 * kh)) * 8;
    *(uint4*)(W16 + dst) = *(uint4*)&h;
}

// ---------------------------------------------------------------------------
// tiny squash kernels (unchanged)
// ---------------------------------------------------------------------------
__global__ __launch_bounds__(256) void k_v1(const float* __restrict__ E1,
                                            float* __restrict__ v1) {
    int t = blockIdx.x * 256 + threadIdx.x;
    float s = E1[t] * (1.0f / 16384.0f);
    float ns = s * s;
    #pragma unroll
    for (int d = 1; d < 16; d <<= 1) ns += __shfl_xor(ns, d);
    v1[t] = s * (sqrtf(ns) / (1.0f + ns));
}

__global__ __launch_bounds__(256) void k_vsum(const float* __restrict__ E,
                                              const float* __restrict__ Z,
                                              const float* __restrict__ v1,
                                              float* __restrict__ vsum) {
    int t = blockIdx.x * 256 + threadIdx.x;
    float s = E[t] / Z[t >> 4];
    float ns = s * s;
    #pragma unroll
    for (int d = 1; d < 16; d <<= 1) ns += __shfl_xor(ns, d);
    vsum[t] = v1[t] + s * (sqrtf(ns) / (1.0f + ns));
}

__global__ __launch_bounds__(256) void k_vout(const float* __restrict__ E,
                                              const float* __restrict__ Z,
                                              float* __restrict__ dst) {
    int t = blockIdx.x * 256 + threadIdx.x;
    float s = E[t] / Z[t >> 4];
    float ns = s * s;
    #pragma unroll
    for (int d = 1; d < 16; d <<= 1) ns += __shfl_xor(ns, d);
    dst[t] = s * (sqrtf(ns) / (1.0f + ns));
}

// ---------------------------------------------------------------------------
// k_route<MODE,REV>: one W16-streaming pass at FULL occupancy.
// Block 256 = 4 waves; grid (16 c, 128 bx) = 2048 blocks, 8/CU co-resident
// (32 waves/CU). Wave wv owns pairs [bx*64 + wv*16, +16) = contiguous 16 KB;
// f[4] rolling prefetch. Per pair: one mfma_f32_32x32x16_f16.
//   MODE 1: Lv per route-parity = 8 fma + shfl_xor(32); e=exp; accE/accZ.
//   MODE 0: accumulate u into the MFMA C operand (E1 = sum_r u).
// D-layout (HW-verified): lane->b=lane&31; reg j->row=(j&3)+8*(j>>2)+4*kh;
// row<16 route-even o=row, row>=16 route-odd o=row-16.
// Live ~56 VGPR < 64-arch cap of launch_bounds(256,8).
// Epilogue: 8.7 KB LDS tree + atomics. REV reverses the bx walk.
// ---------------------------------------------------------------------------
template <int MODE, int REV>
__global__ __launch_bounds__(256, 8)
void k_route(const _Float16* __restrict__ W16,
             const float* __restrict__ x,
             const float* __restrict__ v,
             float* __restrict__ E,
             float* __restrict__ Z) {
    __shared__ float red[4 * 512 + 128];           // 8.7 KB epilogue scratch
    const int c = blockIdx.x;
    const int bxr = (int)blockIdx.y;
    const int bx = REV ? (127 - bxr) : bxr;
    const int tid = threadIdx.x;
    const int wv = tid >> 6;                       // [0,4)
    const int lane = tid & 63;
    const int b = lane & 31;                       // batch (N-col / D-col)
    const int kh = lane >> 5;                      // k-half

    // ---- B fragment from x (single f16) ----
    half8_t Bh;
    {
        const float4* xb = (const float4*)(x + (b * 16 + c) * 16) + kh * 2;
        float4 x0 = xb[0], x1 = xb[1];
        float xv[8] = {x0.x, x0.y, x0.z, x0.w, x1.x, x1.y, x1.z, x1.w};
        #pragma unroll
        for (int j = 0; j < 8; ++j) Bh[j] = (_Float16)xv[j];
    }
    // v slice for this lane: o in {4kh..4kh+3} u {8+4kh..11+4kh}
    float vv[8];
    if (MODE) {
        const float4* vb = (const float4*)(v + (b * 16 + c) * 16);
        float4 v0 = vb[kh], v1 = vb[2 + kh];
        vv[0]=v0.x; vv[1]=v0.y; vv[2]=v0.z; vv[3]=v0.w;
        vv[4]=v1.x; vv[5]=v1.y; vv[6]=v1.z; vv[7]=v1.w;
    }

    f32x16_t a1 = {0.f,0.f,0.f,0.f,0.f,0.f,0.f,0.f,
                   0.f,0.f,0.f,0.f,0.f,0.f,0.f,0.f};
    const f32x16_t z16 = a1;
    float accE[16];
    #pragma unroll
    for (int j = 0; j < 16; ++j) accE[j] = 0.f;
    float accZ0 = 0.f, accZ1 = 0.f;

    // per-lane fragment stream: pair p -> base[p*64]
    const uint4* base = (const uint4*)W16
        + ((size_t)(c * 8192 + bx * 64 + wv * 16)) * 64 + lane;

    uint4 f[4];
    #pragma unroll
    for (int j = 0; j < 4; ++j) f[j] = base[(size_t)j * 64];

    #pragma unroll 4
    for (int p = 0; p < 16; ++p) {
        uint4 cur = f[p & 3];
        if (p + 4 < 16) f[p & 3] = base[(size_t)(p + 4) * 64];
        half8_t Ah;
        *(uint4*)&Ah = cur;
        if (MODE) {
            f32x16_t t = __builtin_amdgcn_mfma_f32_32x32x16_f16(Ah, Bh, z16, 0, 0, 0);
            float pe = 0.f, po = 0.f;
            #pragma unroll
            for (int rb = 0; rb < 4; ++rb) {
                pe += t[rb] * vv[rb] + t[4 + rb] * vv[4 + rb];
                po += t[8 + rb] * vv[rb] + t[12 + rb] * vv[4 + rb];
            }
            pe += __shfl_xor(pe, 32);              // join k-halves (o-halves)
            po += __shfl_xor(po, 32);
            float e0 = __expf(pe), e1 = __expf(po);
            accZ0 += e0;  accZ1 += e1;
            #pragma unroll
            for (int j = 0; j < 8; ++j)  accE[j] += e0 * t[j];
            #pragma unroll
            for (int j = 8; j < 16; ++j) accE[j] += e1 * t[j];
        } else {
            a1 = __builtin_amdgcn_mfma_f32_32x32x16_f16(Ah, Bh, a1, 0, 0, 0);
        }
    }
    if (!MODE) {
        #pragma unroll
        for (int j = 0; j < 16; ++j) accE[j] = a1[j];
    }

    // ---- epilogue: 4-wave LDS tree + atomics ----
    float4 e0 = make_float4(accE[0] + accE[8],  accE[1] + accE[9],
                            accE[2] + accE[10], accE[3] + accE[11]);
    float4 e1 = make_float4(accE[4] + accE[12], accE[5] + accE[13],
                            accE[6] + accE[14], accE[7] + accE[15]);
    *(float4*)&red[wv * 512 + b * 16 + 4 * kh]     = e0;
    *(float4*)&red[wv * 512 + b * 16 + 8 + 4 * kh] = e1;
    if (MODE && kh == 0) red[2048 + wv * 32 + b] = accZ0 + accZ1;
    __syncthreads();
    #pragma unroll
    for (int s = 0; s < 2; ++s) {
        int slot = s * 256 + tid;                  // [0,512)
        float sum = 0.f;
        #pragma unroll
        for (int w2 = 0; w2 < 4; ++w2) sum += red[w2 * 512 + slot];
        atomicAdd(&E[(slot >> 4) * 256 + c * 16 + (slot & 15)], sum);
    }
    if (MODE && tid < 32) {
        float sz = 0.f;
        #pragma unroll
        for (int w2 = 0; w2 < 4; ++w2) sz += red[2048 + w2 * 32 + tid];
        atomicAdd(&Z[tid * 16 + c], sz);
    }
}

// ---------------------------------------------------------------------------
// launch
// ---------------------------------------------------------------------------
extern "C" void kernel_launch(void* const* d_in, const int* in_sizes, int n_in,
                              void* d_out, int out_size, void* d_ws, size_t ws_size,
                              hipStream_t stream) {
    const float* x = (const float*)d_in[0];        // 8192 floats
    const float* W = (const float*)d_in[1];        // 67108864 floats (256 MB)
    float* out = (float*)d_out;                    // 8192 floats
    float* ws = (float*)d_ws;

    float* E1   = ws + 0;          // 8192  (S = sum_r u)
    float* E2   = ws + 8192;       // 8192
    float* Z2   = ws + 16384;      // 512
    float* E3   = ws + 16896;      // 8192
    float* Z3   = ws + 25088;      // 512   (zeroed region ends at 25600)
    float* v1   = ws + 25600;      // 8192
    float* vsum = ws + 33792;      // 8192
    _Float16* W16 = (_Float16*)(ws + 65536);       // 64M halves = 128 MB

    hipMemsetAsync(ws, 0, 25600 * sizeof(float), stream);

    // one-time dense fp32->fp16 repack
    k_conv<<<32768, 256, 0, stream>>>((const float4*)W, W16);

    // iter 1: S = sum_r u (uniform routing), W16 pass 1 (forward)
    k_route<0, 0><<<dim3(16, 128), 256, 0, stream>>>(W16, x, v1, E1, Z2);
    k_v1<<<32, 256, 0, stream>>>(E1, v1);          // v1 = squash(S/R)

    // iter 2: logits = <u, v1>, W16 pass 2 (reverse: L3-warm tail)
    k_route<1, 1><<<dim3(16, 128), 256, 0, stream>>>(W16, x, v1, E2, Z2);
    k_vsum<<<32, 256, 0, stream>>>(E2, Z2, v1, vsum);  // vsum = v1 + squash(E2/Z2)

    // iter 3: logits = <u, v1+v2>, W16 pass 3 (forward)
    k_route<1, 0><<<dim3(16, 128), 256, 0, stream>>>(W16, x, vsum, E3, Z3);
    k_vout<<<32, 256, 0, stream>>>(E3, Z3, out);
}

// Round 21
// 537.125 us; speedup vs baseline: 1.4735x; 1.4735x over previous
//
#include <hip/hip_runtime.h>
#include <math.h>

// B=32, R=16384, C=16, IC=16, OC=16, 3 routing iterations.
// x: (B,C,IC) fp32; W: (R,C,OC,IC) fp32 (256 MB); out: (B,C,OC) fp32.
//
// R21: R20 PROVED 32 waves/CU delivers 3.7-3.8 TB/s (vs 1.7 at 16 waves) --
// but launch_bounds(256,8) caps at 32 arch VGPRs (allocator law: (512/w)/2)
// and the ~56-reg live set spilled (WRITE 449 MB, FETCH 303 MB). This round
// keeps the occupancy and diets the live set under the 64-total budget:
//   - R11 parity-fold in-loop: aF0[4]+aF1[4] replaces accE[16]   (-8)
//   - v in padded LDS table Vl[b*17+o] (17-stride: 2 lanes/bank = free,
//     re-read per pair instead of held live)                      (-8)
//   - prefetch depth 2 (f0/f1); 2 KB/wave x 32 waves/CU in flight (-8)
//   - MFMA result t (16) sits in the AGPR half of the unified file
// Est. live ~50 < 64. Carried: W16 fragment repack (R17), single-term fp16
// MFMA (absmax 3.9e-3 vs threshold 1.5e-2), 4-wave LDS-tree epilogue (R20),
// no cooperative launch (R12), no fusion barriers (R16), split conv (R19
// fused-convsum regressed). Accounting: total = ~160us workspace-poison
// fill (harness, unavoidable) + conv ~60 + 3 routes + smalls.

typedef _Float16 half8_t __attribute__((ext_vector_type(8)));
typedef float f32x16_t __attribute__((ext_vector_type(16)));

// ---------------------------------------------------------------------------
// k_conv: W fp32 -> W16 fp16 fragment layout (R17/R18-proven).
// W16 layout (halves): ((c*8192 + (r>>1))*64 + ((r&1)*16 + o + 32*kh))*8,
// element j = W[r][c][o][8kh+j] -- the mfma_32x32x16 A-fragment.
// ---------------------------------------------------------------------------
__global__ __launch_bounds__(256) void k_conv(const float4* __restrict__ W4,
                                              _Float16* __restrict__ W16) {
    int t = blockIdx.x * 256 + threadIdx.x;        // [0, 8388608)
    int kh = t & 1, o = (t >> 1) & 15, c = (t >> 5) & 15, r = t >> 9;
    float4 a = W4[(size_t)t * 2], b = W4[(size_t)t * 2 + 1];
    half8_t h;
    h[0] = (_Float16)a.x; h[1] = (_Float16)a.y; h[2] = (_Float16)a.z; h[3] = (_Float16)a.w;
    h[4] = (_Float16)b.x; h[5] = (_Float16)b.y; h[6] = (_Float16)b.z; h[7] = (_Float16)b.w;
    size_t dst = ((size_t)(c * 8192 + (r >> 1)) * 64
                  + ((r & 1) * 16 + o + 32 * kh)) * 8;
    *(uint4*)(W16 + dst) = *(uint4*)&h;
}

// ---------------------------------------------------------------------------
// tiny squash kernels (unchanged)
// ---------------------------------------------------------------------------
__global__ __launch_bounds__(256) void k_v1(const float* __restrict__ E1,
                                            float* __restrict__ v1) {
    int t = blockIdx.x * 256 + threadIdx.x;
    float s = E1[t] * (1.0f / 16384.0f);
    float ns = s * s;
    #pragma unroll
    for (int d = 1; d < 16; d <<= 1) ns += __shfl_xor(ns, d);
    v1[t] = s * (sqrtf(ns) / (1.0f + ns));
}

__global__ __launch_bounds__(256) void k_vsum(const float* __restrict__ E,
                                              const float* __restrict__ Z,
                                              const float* __restrict__ v1,
                                              float* __restrict__ vsum) {
    int t = blockIdx.x * 256 + threadIdx.x;
    float s = E[t] / Z[t >> 4];
    float ns = s * s;
    #pragma unroll
    for (int d = 1; d < 16; d <<= 1) ns += __shfl_xor(ns, d);
    vsum[t] = v1[t] + s * (sqrtf(ns) / (1.0f + ns));
}

__global__ __launch_bounds__(256) void k_vout(const float* __restrict__ E,
                                              const float* __restrict__ Z,
                                              float* __restrict__ dst) {
    int t = blockIdx.x * 256 + threadIdx.x;
    float s = E[t] / Z[t >> 4];
    float ns = s * s;
    #pragma unroll
    for (int d = 1; d < 16; d <<= 1) ns += __shfl_xor(ns, d);
    dst[t] = s * (sqrtf(ns) / (1.0f + ns));
}

// ---------------------------------------------------------------------------
// k_route<MODE,REV>: one W16-streaming pass at 32 waves/CU, dieted live set.
// Block 256 = 4 waves; grid (16 c, 128 bx) = 2048 blocks, 8/CU co-resident.
// Wave wv owns pairs [bx*64 + wv*16, +16) = contiguous 16 KB; f0/f1 rolling
// prefetch. Per pair: one mfma_f32_32x32x16_f16.
//   MODE 1: pe/po via Vl reads (8 per pair, conflict-free by 17-stride);
//           Lv = +shfl_xor(32); e=exp; aF0/aF1 parity-fold accumulate.
//   MODE 0: accumulate u into the MFMA C operand; parity-fold at end.
// D-layout (HW-verified): lane->b=lane&31; reg j->row=(j&3)+8*(j>>2)+4*kh;
// row<16 route-even o=row, row>=16 route-odd o=row-16.
//   aF0[rb] accumulates o=4kh+rb (even e0 + odd e1 contributions);
//   aF1[rb] accumulates o=8+4kh+rb.  (Linear == R11's accE + end-fold.)
// Epilogue: 8.7 KB LDS tree + atomics. REV reverses the bx walk.
// ---------------------------------------------------------------------------
template <int MODE, int REV>
__global__ __launch_bounds__(256, 8)
void k_route(const _Float16* __restrict__ W16,
             const float* __restrict__ x,
             const float* __restrict__ v,
             float* __restrict__ E,
             float* __restrict__ Z) {
    __shared__ float red[4 * 512 + 128];           // 8.7 KB epilogue scratch
    __shared__ float Vl[544];                      // v table, stride 17 (2.2 KB)
    const int c = blockIdx.x;
    const int bxr = (int)blockIdx.y;
    const int bx = REV ? (127 - bxr) : bxr;
    const int tid = threadIdx.x;
    const int wv = tid >> 6;                       // [0,4)
    const int lane = tid & 63;
    const int b = lane & 31;                       // batch (N-col / D-col)
    const int kh = lane >> 5;                      // k-half

    if (MODE) {
        #pragma unroll
        for (int s = 0; s < 2; ++s) {
            int sl = s * 256 + tid;                // [0,512)
            Vl[(sl >> 4) * 17 + (sl & 15)] = v[((sl >> 4) * 16 + c) * 16 + (sl & 15)];
        }
    }

    // ---- B fragment from x (single f16) ----
    half8_t Bh;
    {
        const float4* xb = (const float4*)(x + (b * 16 + c) * 16) + kh * 2;
        float4 x0 = xb[0], x1 = xb[1];
        float xv[8] = {x0.x, x0.y, x0.z, x0.w, x1.x, x1.y, x1.z, x1.w};
        #pragma unroll
        for (int j = 0; j < 8; ++j) Bh[j] = (_Float16)xv[j];
    }
    if (MODE) __syncthreads();                     // Vl ready

    f32x16_t a1 = {0.f,0.f,0.f,0.f,0.f,0.f,0.f,0.f,
                   0.f,0.f,0.f,0.f,0.f,0.f,0.f,0.f};
    const f32x16_t z16 = a1;
    float aF0[4] = {0.f, 0.f, 0.f, 0.f};
    float aF1[4] = {0.f, 0.f, 0.f, 0.f};
    float accZ0 = 0.f, accZ1 = 0.f;

    // per-lane fragment stream: pair p -> base[p*64]; Vl row for this lane
    const uint4* base = (const uint4*)W16
        + ((size_t)(c * 8192 + bx * 64 + wv * 16)) * 64 + lane;
    const int vr = b * 17 + 4 * kh;

    uint4 f0 = base[0];
    uint4 f1 = base[64];

    #pragma unroll 2
    for (int p = 0; p < 16; ++p) {
        uint4 cur = f0;
        f0 = f1;
        if (p + 2 < 16) f1 = base[(size_t)(p + 2) * 64];
        half8_t Ah;
        *(uint4*)&Ah = cur;
        if (MODE) {
            f32x16_t t = __builtin_amdgcn_mfma_f32_32x32x16_f16(Ah, Bh, z16, 0, 0, 0);
            float pe = 0.f, po = 0.f;
            #pragma unroll
            for (int rb = 0; rb < 4; ++rb) {
                float va = Vl[vr + rb];            // o = 4kh+rb
                float vb2 = Vl[vr + 8 + rb];       // o = 8+4kh+rb
                pe += t[rb] * va + t[4 + rb] * vb2;
                po += t[8 + rb] * va + t[12 + rb] * vb2;
            }
            pe += __shfl_xor(pe, 32);              // join k-halves (o-halves)
            po += __shfl_xor(po, 32);
            float e0 = __expf(pe), e1 = __expf(po);
            accZ0 += e0;  accZ1 += e1;
            #pragma unroll
            for (int rb = 0; rb < 4; ++rb) {
                aF0[rb] += e0 * t[rb]     + e1 * t[8 + rb];
                aF1[rb] += e0 * t[4 + rb] + e1 * t[12 + rb];
            }
        } else {
            a1 = __builtin_amdgcn_mfma_f32_32x32x16_f16(Ah, Bh, a1, 0, 0, 0);
        }
    }
    if (!MODE) {
        #pragma unroll
        for (int rb = 0; rb < 4; ++rb) {
            aF0[rb] = a1[rb]     + a1[8 + rb];
            aF1[rb] = a1[4 + rb] + a1[12 + rb];
        }
    }

    // ---- epilogue: 4-wave LDS tree + atomics ----
    *(float4*)&red[wv * 512 + b * 16 + 4 * kh] =
        make_float4(aF0[0], aF0[1], aF0[2], aF0[3]);
    *(float4*)&red[wv * 512 + b * 16 + 8 + 4 * kh] =
        make_float4(aF1[0], aF1[1], aF1[2], aF1[3]);
    if (MODE && kh == 0) red[2048 + wv * 32 + b] = accZ0 + accZ1;
    __syncthreads();
    #pragma unroll
    for (int s = 0; s < 2; ++s) {
        int slot = s * 256 + tid;                  // [0,512)
        float sum = 0.f;
        #pragma unroll
        for (int w2 = 0; w2 < 4; ++w2) sum += red[w2 * 512 + slot];
        atomicAdd(&E[(slot >> 4) * 256 + c * 16 + (slot & 15)], sum);
    }
    if (MODE && tid < 32) {
        float sz = 0.f;
        #pragma unroll
        for (int w2 = 0; w2 < 4; ++w2) sz += red[2048 + w2 * 32 + tid];
        atomicAdd(&Z[tid * 16 + c], sz);
    }
}

// ---------------------------------------------------------------------------
// launch
// ---------------------------------------------------------------------------
extern "C" void kernel_launch(void* const* d_in, const int* in_sizes, int n_in,
                              void* d_out, int out_size, void* d_ws, size_t ws_size,
                              hipStream_t stream) {
    const float* x = (const float*)d_in[0];        // 8192 floats
    const float* W = (const float*)d_in[1];        // 67108864 floats (256 MB)
    float* out = (float*)d_out;                    // 8192 floats
    float* ws = (float*)d_ws;

    float* E1   = ws + 0;          // 8192  (S = sum_r u)
    float* E2   = ws + 8192;       // 8192
    float* Z2   = ws + 16384;      // 512
    float* E3   = ws + 16896;      // 8192
    float* Z3   = ws + 25088;      // 512   (zeroed region ends at 25600)
    float* v1   = ws + 25600;      // 8192
    float* vsum = ws + 33792;      // 8192
    _Float16* W16 = (_Float16*)(ws + 65536);       // 64M halves = 128 MB

    hipMemsetAsync(ws, 0, 25600 * sizeof(float), stream);

    // one-time dense fp32->fp16 repack
    k_conv<<<32768, 256, 0, stream>>>((const float4*)W, W16);

    // iter 1: S = sum_r u (uniform routing), W16 pass 1 (forward)
    k_route<0, 0><<<dim3(16, 128), 256, 0, stream>>>(W16, x, v1, E1, Z2);
    k_v1<<<32, 256, 0, stream>>>(E1, v1);          // v1 = squash(S/R)

    // iter 2: logits = <u, v1>, W16 pass 2 (reverse: L3-warm tail)
    k_route<1, 1><<<dim3(16, 128), 256, 0, stream>>>(W16, x, v1, E2, Z2);
    k_vsum<<<32, 256, 0, stream>>>(E2, Z2, v1, vsum);  // vsum = v1 + squash(E2/Z2)

    // iter 3: logits = <u, v1+v2>, W16 pass 3 (forward)
    k_route<1, 0><<<dim3(16, 128), 256, 0, stream>>>(W16, x, vsum, E3, Z3);
    k_vout<<<32, 256, 0, stream>>>(E3, Z3, out);
}

// Round 22
// 536.147 us; speedup vs baseline: 1.4762x; 1.0018x over previous
//
#include <hip/hip_runtime.h>
#include <math.h>

// B=32, R=16384, C=16, IC=16, OC=16, 3 routing iterations.
// x: (B,C,IC) fp32; W: (R,C,OC,IC) fp32 (256 MB); out: (B,C,OC) fp32.
//
// R22: high-occupancy AND spill-free. Allocator law (R4/R5/R6/R20):
// granted_arch = 256/waves_requested. Unavoidable live = t(16)+Bh(4)+aF(8)+
// accZ(2)+addr(~8) ~= 38-40. Removable: the f0/f1 VGPR prefetch (8) ->
// global_load_lds DMA staging (R14-proven; W16 fragment layout makes it a
// dense 1 KB/wave transfer, LINEAR LDS dest + linear read-back, no swizzle).
// launch_bounds(256,6) -> ~42 arch >= live -> spill-free at 24+ waves/CU
// (19 KB LDS/block -> up to 8 blocks/CU). R20 proved concurrency is the
// memory-throughput lever (16w: 1.7 TB/s; 32w: 3.6-3.8 TB/s raw).
// Carried: W16 fragment repack (R17), single-term fp16 MFMA (absmax 3.9e-3
// vs threshold 1.5e-2), Vl 17-stride LDS v-table + in-loop parity fold
// (R21), 4-wave LDS-tree epilogue (R20), split conv (R19 regressed fused),
// no cooperative launch (R12), no fusion barriers (R16).
// Accounting: total = ~160us harness poison-fill + conv ~60 + 3 routes +
// smalls ~15.

typedef _Float16 half8_t __attribute__((ext_vector_type(8)));
typedef float f32x16_t __attribute__((ext_vector_type(16)));

// async global->LDS, 16 B per lane. LDS dest = wave-uniform base + lane*16.
__device__ __forceinline__ void gload_lds16(const void* g, void* l) {
  __builtin_amdgcn_global_load_lds(
      (const __attribute__((address_space(1))) unsigned int*)g,
      (__attribute__((address_space(3))) unsigned int*)l, 16, 0, 0);
}

// ---------------------------------------------------------------------------
// k_conv: W fp32 -> W16 fp16 fragment layout (R17/R18-proven).
// W16 layout (halves): ((c*8192 + (r>>1))*64 + ((r&1)*16 + o + 32*kh))*8,
// element j = W[r][c][o][8kh+j] -- the mfma_32x32x16 A-fragment.
// ---------------------------------------------------------------------------
__global__ __launch_bounds__(256) void k_conv(const float4* __restrict__ W4,
                                              _Float16* __restrict__ W16) {
    int t = blockIdx.x * 256 + threadIdx.x;        // [0, 8388608)
    int kh = t & 1, o = (t >> 1) & 15, c = (t >> 5) & 15, r = t >> 9;
    float4 a = W4[(size_t)t * 2], b = W4[(size_t)t * 2 + 1];
    half8_t h;
    h[0] = (_Float16)a.x; h[1] = (_Float16)a.y; h[2] = (_Float16)a.z; h[3] = (_Float16)a.w;
    h[4] = (_Float16)b.x; h[5] = (_Float16)b.y; h[6] = (_Float16)b.z; h[7] = (_Float16)b.w;
    size_t dst = ((size_t)(c * 8192 + (r >> 1)) * 64
                  + ((r & 1) * 16 + o + 32 * kh)) * 8;
    *(uint4*)(W16 + dst) = *(uint4*)&h;
}

// ---------------------------------------------------------------------------
// tiny squash kernels (unchanged)
// ---------------------------------------------------------------------------
__global__ __launch_bounds__(256) void k_v1(const float* __restrict__ E1,
                                            float* __restrict__ v1) {
    int t = blockIdx.x * 256 + threadIdx.x;
    float s = E1[t] * (1.0f / 16384.0f);
    float ns = s * s;
    #pragma unroll
    for (int d = 1; d < 16; d <<= 1) ns += __shfl_xor(ns, d);
    v1[t] = s * (sqrtf(ns) / (1.0f + ns));
}

__global__ __launch_bounds__(256) void k_vsum(const float* __restrict__ E,
                                              const float* __restrict__ Z,
                                              const float* __restrict__ v1,
                                              float* __restrict__ vsum) {
    int t = blockIdx.x * 256 + threadIdx.x;
    float s = E[t] / Z[t >> 4];
    float ns = s * s;
    #pragma unroll
    for (int d = 1; d < 16; d <<= 1) ns += __shfl_xor(ns, d);
    vsum[t] = v1[t] + s * (sqrtf(ns) / (1.0f + ns));
}

__global__ __launch_bounds__(256) void k_vout(const float* __restrict__ E,
                                              const float* __restrict__ Z,
                                              float* __restrict__ dst) {
    int t = blockIdx.x * 256 + threadIdx.x;
    float s = E[t] / Z[t >> 4];
    float ns = s * s;
    #pragma unroll
    for (int d = 1; d < 16; d <<= 1) ns += __shfl_xor(ns, d);
    dst[t] = s * (sqrtf(ns) / (1.0f + ns));
}

// ---------------------------------------------------------------------------
// k_route<MODE,REV>: W16-streaming pass, DMA-staged, high occupancy.
// Block 256 = 4 waves; grid (16 c, 128 bx) = 2048 blocks. Wave wv owns pairs
// [bx*64 + wv*16, +16) = contiguous 16 KB of W16. Per pair: one dense 1 KB
// gload_lds16 into the wave's 2x1KB double buffer (no VGPRs held, no
// barriers -- wave-private), vmcnt(1), one ds_read_b128 (lane l reads its
// own 16 B = its whole A-fragment; linear, conflict-free 2/bank), one
// mfma_f32_32x32x16_f16.
//   MODE 1: pe/po via Vl reads (17-stride = 2 lanes/bank, free);
//           Lv = +shfl_xor(32); e=exp; aF0/aF1 parity-fold accumulate.
//   MODE 0: accumulate u into the MFMA C operand; parity-fold at end.
// D-layout (HW-verified): lane->b=lane&31; reg j->row=(j&3)+8*(j>>2)+4*kh;
// row<16 route-even o=row, row>=16 route-odd o=row-16.
// Live ~38-40 arch VGPR <= ~42 granted by launch_bounds(256,6).
// LDS: 8 KB Wl + 8.7 KB red + 2.2 KB Vl = 19 KB -> up to 8 blocks/CU.
// ---------------------------------------------------------------------------
template <int MODE, int REV>
__global__ __launch_bounds__(256, 6)
void k_route(const _Float16* __restrict__ W16,
             const float* __restrict__ x,
             const float* __restrict__ v,
             float* __restrict__ E,
             float* __restrict__ Z) {
    __shared__ uint4 Wl[4][2][64];                 // 8 KB: per-wave 2 x 1 KB
    __shared__ float red[4 * 512 + 128];           // 8.7 KB epilogue scratch
    __shared__ float Vl[544];                      // v table, stride 17
    const int c = blockIdx.x;
    const int bxr = (int)blockIdx.y;
    const int bx = REV ? (127 - bxr) : bxr;
    const int tid = threadIdx.x;
    const int wv = tid >> 6;                       // [0,4)
    const int lane = tid & 63;
    const int b = lane & 31;                       // batch (N-col / D-col)
    const int kh = lane >> 5;                      // k-half

    if (MODE) {
        #pragma unroll
        for (int s = 0; s < 2; ++s) {
            int sl = s * 256 + tid;                // [0,512)
            Vl[(sl >> 4) * 17 + (sl & 15)] = v[((sl >> 4) * 16 + c) * 16 + (sl & 15)];
        }
    }

    // ---- B fragment from x (single f16) ----
    half8_t Bh;
    {
        const float4* xb = (const float4*)(x + (b * 16 + c) * 16) + kh * 2;
        float4 x0 = xb[0], x1 = xb[1];
        float xv[8] = {x0.x, x0.y, x0.z, x0.w, x1.x, x1.y, x1.z, x1.w};
        #pragma unroll
        for (int j = 0; j < 8; ++j) Bh[j] = (_Float16)xv[j];
    }
    __syncthreads();                               // Vl ready (also MODE 0 ok)

    f32x16_t a1 = {0.f,0.f,0.f,0.f,0.f,0.f,0.f,0.f,
                   0.f,0.f,0.f,0.f,0.f,0.f,0.f,0.f};
    const f32x16_t z16 = a1;
    float aF0[4] = {0.f, 0.f, 0.f, 0.f};
    float aF1[4] = {0.f, 0.f, 0.f, 0.f};
    float accZ0 = 0.f, accZ1 = 0.f;

    // per-lane global source: pair p -> wsrc + p*512 halves + lane*8
    const _Float16* wsrc = W16
        + ((size_t)(c * 8192 + bx * 64 + wv * 16)) * 512 + lane * 8;
    const int vr = b * 17 + 4 * kh;

    gload_lds16(wsrc, &Wl[wv][0][0]);              // stage pair 0

    #pragma unroll 2
    for (int p = 0; p < 16; ++p) {
        if (p < 15)
            gload_lds16(wsrc + (size_t)(p + 1) * 512, &Wl[wv][(p + 1) & 1][0]);
        if (p < 15) asm volatile("s_waitcnt vmcnt(1)" ::: "memory");
        else        asm volatile("s_waitcnt vmcnt(0)" ::: "memory");
        uint4 cur = *(const uint4*)&Wl[wv][p & 1][lane];   // ds_read_b128
        half8_t Ah;
        *(uint4*)&Ah = cur;
        if (MODE) {
            f32x16_t t = __builtin_amdgcn_mfma_f32_32x32x16_f16(Ah, Bh, z16, 0, 0, 0);
            float pe = 0.f, po = 0.f;
            #pragma unroll
            for (int rb = 0; rb < 4; ++rb) {
                float va = Vl[vr + rb];            // o = 4kh+rb
                float vb2 = Vl[vr + 8 + rb];       // o = 8+4kh+rb
                pe += t[rb] * va + t[4 + rb] * vb2;
                po += t[8 + rb] * va + t[12 + rb] * vb2;
            }
            pe += __shfl_xor(pe, 32);              // join k-halves (o-halves)
            po += __shfl_xor(po, 32);
            float e0 = __expf(pe), e1 = __expf(po);
            accZ0 += e0;  accZ1 += e1;
            #pragma unroll
            for (int rb = 0; rb < 4; ++rb) {
                aF0[rb] += e0 * t[rb]     + e1 * t[8 + rb];
                aF1[rb] += e0 * t[4 + rb] + e1 * t[12 + rb];
            }
        } else {
            a1 = __builtin_amdgcn_mfma_f32_32x32x16_f16(Ah, Bh, a1, 0, 0, 0);
        }
    }
    if (!MODE) {
        #pragma unroll
        for (int rb = 0; rb < 4; ++rb) {
            aF0[rb] = a1[rb]     + a1[8 + rb];
            aF1[rb] = a1[4 + rb] + a1[12 + rb];
        }
    }

    // ---- epilogue: 4-wave LDS tree + atomics ----
    *(float4*)&red[wv * 512 + b * 16 + 4 * kh] =
        make_float4(aF0[0], aF0[1], aF0[2], aF0[3]);
    *(float4*)&red[wv * 512 + b * 16 + 8 + 4 * kh] =
        make_float4(aF1[0], aF1[1], aF1[2], aF1[3]);
    if (MODE && kh == 0) red[2048 + wv * 32 + b] = accZ0 + accZ1;
    __syncthreads();
    #pragma unroll
    for (int s = 0; s < 2; ++s) {
        int slot = s * 256 + tid;                  // [0,512)
        float sum = 0.f;
        #pragma unroll
        for (int w2 = 0; w2 < 4; ++w2) sum += red[w2 * 512 + slot];
        atomicAdd(&E[(slot >> 4) * 256 + c * 16 + (slot & 15)], sum);
    }
    if (MODE && tid < 32) {
        float sz = 0.f;
        #pragma unroll
        for (int w2 = 0; w2 < 4; ++w2) sz += red[2048 + w2 * 32 + tid];
        atomicAdd(&Z[tid * 16 + c], sz);
    }
}

// ---------------------------------------------------------------------------
// launch
// ---------------------------------------------------------------------------
extern "C" void kernel_launch(void* const* d_in, const int* in_sizes, int n_in,
                              void* d_out, int out_size, void* d_ws, size_t ws_size,
                              hipStream_t stream) {
    const float* x = (const float*)d_in[0];        // 8192 floats
    const float* W = (const float*)d_in[1];        // 67108864 floats (256 MB)
    float* out = (float*)d_out;                    // 8192 floats
    float* ws = (float*)d_ws;

    float* E1   = ws + 0;          // 8192  (S = sum_r u)
    float* E2   = ws + 8192;       // 8192
    float* Z2   = ws + 16384;      // 512
    float* E3   = ws + 16896;      // 8192
    float* Z3   = ws + 25088;      // 512   (zeroed region ends at 25600)
    float* v1   = ws + 25600;      // 8192
    float* vsum = ws + 33792;      // 8192
    _Float16* W16 = (_Float16*)(ws + 65536);       // 64M halves = 128 MB

    hipMemsetAsync(ws, 0, 25600 * sizeof(float), stream);

    // one-time dense fp32->fp16 repack
    k_conv<<<32768, 256, 0, stream>>>((const float4*)W, W16);

    // iter 1: S = sum_r u (uniform routing), W16 pass 1 (forward)
    k_route<0, 0><<<dim3(16, 128), 256, 0, stream>>>(W16, x, v1, E1, Z2);
    k_v1<<<32, 256, 0, stream>>>(E1, v1);          // v1 = squash(S/R)

    // iter 2: logits = <u, v1>, W16 pass 2 (reverse: L3-warm tail)
    k_route<1, 1><<<dim3(16, 128), 256, 0, stream>>>(W16, x, v1, E2, Z2);
    k_vsum<<<32, 256, 0, stream>>>(E2, Z2, v1, vsum);  // vsum = v1 + squash(E2/Z2)

    // iter 3: logits = <u, v1+v2>, W16 pass 3 (forward)
    k_route<1, 0><<<dim3(16, 128), 256, 0, stream>>>(W16, x, vsum, E3, Z3);
    k_vout<<<32, 256, 0, stream>>>(E3, Z3, out);
}